// Round 2
// baseline (312.102 us; speedup 1.0000x reference)
//
#include <hip/hip_runtime.h>

#define S 32
#define H 768
#define IDIM 768
#define E 32
#define K 4
#define TWO_I 1536
#define LIMIT 7.0f
#define ALPHA 1.702f
#define EPS 1e-5f
#define CHUNK 8

__device__ inline float dot4(float4 a, float4 b) {
  return a.x*b.x + a.y*b.y + a.z*b.z + a.w*b.w;
}

// Co-reduce 4 per-lane accumulators across the 64-lane wave.
// Result: sum of acc g lives in all lanes of group [g*16, g*16+16).
// 7 shuffles for 4 outputs (vs 24 for 4 independent butterflies).
__device__ inline float coreduce4(float a0, float a1, float a2, float a3, int lane) {
  const bool hi32 = (lane & 32) != 0;
  float s0 = hi32 ? a2 : a0;
  float o0 = hi32 ? a0 : a2;
  float s1 = hi32 ? a3 : a1;
  float o1 = hi32 ? a1 : a3;
  s0 += __shfl_xor(o0, 32);
  s1 += __shfl_xor(o1, 32);
  const bool hi16 = (lane & 16) != 0;
  float u  = hi16 ? s1 : s0;
  float ov = hi16 ? s0 : s1;
  u += __shfl_xor(ov, 16);
  u += __shfl_xor(u, 8);
  u += __shfl_xor(u, 4);
  u += __shfl_xor(u, 2);
  u += __shfl_xor(u, 1);
  return u;
}

// ---------------- kernel 1: RMSNorm + router (top-4 + softmax) ------
// grid = S blocks, 256 threads
__global__ void k_norm_router(const float* __restrict__ x,
                              const float* __restrict__ norm_scale,
                              const float* __restrict__ gate_w,
                              const float* __restrict__ gate_b,
                              float* __restrict__ t_out,
                              float* __restrict__ wt_out,
                              int* __restrict__ idx_out) {
  __shared__ float t_s[H];
  __shared__ float red_s[4];
  __shared__ float logit_s[E];
  const int b = blockIdx.x;
  const int tid = threadIdx.x;
  const int lane = tid & 63, wave = tid >> 6;

  float v0 = x[b*H + tid];
  float v1 = x[b*H + tid + 256];
  float v2 = x[b*H + tid + 512];
  float ss = v0*v0 + v1*v1 + v2*v2;
#pragma unroll
  for (int o = 32; o; o >>= 1) ss += __shfl_xor(ss, o);
  if (lane == 0) red_s[wave] = ss;
  __syncthreads();
  float mean = (red_s[0] + red_s[1] + red_s[2] + red_s[3]) * (1.0f/(float)H) + EPS;
  float rs = rsqrtf(mean);
  rs = rs * (1.5f - 0.5f*mean*rs*rs);   // Newton refine for fp32-accurate rsqrt
  float t0 = v0*rs*norm_scale[tid];
  float t1 = v1*rs*norm_scale[tid+256];
  float t2 = v2*rs*norm_scale[tid+512];
  t_s[tid] = t0; t_s[tid+256] = t1; t_s[tid+512] = t2;
  t_out[b*H+tid] = t0; t_out[b*H+tid+256] = t1; t_out[b*H+tid+512] = t2;
  __syncthreads();

  // logits: 4 waves, experts wave, wave+4, ...
  for (int e = wave; e < E; e += 4) {
    const float* gw = gate_w + e*H;
    float s = 0.f;
#pragma unroll
    for (int j = 0; j < H/64; ++j) {
      int p = lane + j*64;
      s += gw[p] * t_s[p];
    }
#pragma unroll
    for (int o = 32; o; o >>= 1) s += __shfl_xor(s, o);
    if (lane == 0) logit_s[e] = s + gate_b[e];
  }
  __syncthreads();

  if (tid == 0) {
    float lg[E];
    for (int e = 0; e < E; ++e) lg[e] = logit_s[e];
    float vals[K]; int idxs[K];
    for (int k = 0; k < K; ++k) {
      float best = -3.4e38f; int bi = 0;
      for (int e = 0; e < E; ++e)
        if (lg[e] > best) { best = lg[e]; bi = e; }  // strict > == lax.top_k tie-break
      vals[k] = best; idxs[k] = bi; lg[bi] = -3.4e38f;
    }
    float m = vals[0], sum = 0.f, w[K];
    for (int k = 0; k < K; ++k) { w[k] = expf(vals[k]-m); sum += w[k]; }
    float inv = 1.f/sum;
    for (int k = 0; k < K; ++k) {
      wt_out[b*K+k] = w[k]*inv;
      idx_out[b*K+k] = idxs[k];
    }
  }
}

// Deterministic per-expert assignment list via ballot compaction (wave 0).
// list_s gets assignment ids (b*K+k) in ascending order; returns n via n_s.
#define BUILD_LIST(eexpr)                                                   \
  if (tid < 64) {                                                           \
    int a0 = idx_all[tid];                                                  \
    int a1 = idx_all[tid + 64];                                             \
    unsigned long long m0 = __ballot(a0 == (eexpr));                        \
    unsigned long long m1 = __ballot(a1 == (eexpr));                        \
    unsigned long long below = (1ULL << tid) - 1ULL;                        \
    if (a0 == (eexpr)) list_s[__popcll(m0 & below)] = tid;                  \
    if (a1 == (eexpr)) list_s[__popcll(m0) + __popcll(m1 & below)] = tid + 64; \
    if (tid == 0) n_s = (int)(__popcll(m0) + __popcll(m1));                 \
  }                                                                         \
  __syncthreads();

// ---------------- kernel 2: expert-grouped GEMV1 + SwiGLU ----------
// grid = (E, TWO_I/32 = 48), 256 threads. 32 rows/block, 8 rows/wave.
__global__ void k_gemv1(const float* __restrict__ w1,
                        const float* __restrict__ b1,
                        const float* __restrict__ t,
                        const int* __restrict__ idx_all,
                        float* __restrict__ act) {
  const int e = blockIdx.x;
  const int tid = threadIdx.x;
  const int lane = tid & 63, wave = tid >> 6;
  __shared__ float t_lds[CHUNK*H];   // 24 KB
  __shared__ float h_lds[32*CHUNK];  // 1 KB
  __shared__ int list_s[S];
  __shared__ int n_s;

  BUILD_LIST(e)
  const int n = n_s;
  if (n == 0) return;
  const int row0 = blockIdx.y * 32;

  for (int c0 = 0; c0 < n; c0 += CHUNK) {
    const int cn = min(CHUNK, n - c0);
    for (int q = tid; q < cn*(H/4); q += 256) {
      int j = q / (H/4), p = q - j*(H/4);
      int bt = list_s[c0+j] >> 2;
      ((float4*)(t_lds + j*H))[p] = ((const float4*)(t + (size_t)bt*H))[p];
    }
    __syncthreads();

#pragma unroll
    for (int rt4 = 0; rt4 < 2; ++rt4) {
      const int lrow = wave*8 + rt4*4;
      const int r = row0 + lrow;
      float4 wv[4][3]; float bias[4];
#pragma unroll
      for (int rr = 0; rr < 4; ++rr) {
        const float4* row = (const float4*)(w1 + ((size_t)e*TWO_I + r + rr)*H);
        wv[rr][0] = row[lane]; wv[rr][1] = row[lane+64]; wv[rr][2] = row[lane+128];
        bias[rr] = b1[(size_t)e*TWO_I + r + rr];
      }
      for (int j = 0; j < cn; ++j) {
        const float4* tv = (const float4*)(t_lds + j*H);
        float4 x0 = tv[lane], x1 = tv[lane+64], x2 = tv[lane+128];
        float a0 = dot4(wv[0][0],x0) + dot4(wv[0][1],x1) + dot4(wv[0][2],x2);
        float a1 = dot4(wv[1][0],x0) + dot4(wv[1][1],x1) + dot4(wv[1][2],x2);
        float a2 = dot4(wv[2][0],x0) + dot4(wv[2][1],x1) + dot4(wv[2][2],x2);
        float a3 = dot4(wv[3][0],x0) + dot4(wv[3][1],x1) + dot4(wv[3][2],x2);
        float u = coreduce4(a0, a1, a2, a3, lane);
        const bool hi32 = (lane & 32) != 0, hi16 = (lane & 16) != 0;
        float bsel = hi32 ? (hi16 ? bias[3] : bias[2]) : (hi16 ? bias[1] : bias[0]);
        if ((lane & 15) == 0)
          h_lds[(lrow + (lane >> 4))*CHUNK + j] = u + bsel;
      }
    }
    __syncthreads();

    // interleaved SwiGLU: local even row 2c -> glu, odd row 2c+1 -> lin
    for (int q = tid; q < 16*cn; q += 256) {
      int c = q & 15, j = q >> 4;
      float he = h_lds[(2*c)*CHUNK + j];
      float ho = h_lds[(2*c+1)*CHUNK + j];
      float xg = fminf(he, LIMIT);
      float xl = fminf(fmaxf(ho, -LIMIT), LIMIT);
      float sig = 1.f/(1.f + expf(-ALPHA*xg));
      int aid = list_s[c0 + j];
      act[(size_t)aid*IDIM + (row0 >> 1) + c] = xg*sig*(xl + 1.f);
    }
    __syncthreads();
  }
}

// ---------------- kernel 3: expert-grouped GEMV2 -------------------
// grid = (E, H/16 = 48), 256 threads. 16 rows/block, 4 rows/wave.
__global__ void k_gemv2(const float* __restrict__ w2,
                        const float* __restrict__ b2,
                        const float* __restrict__ act,
                        const int* __restrict__ idx_all,
                        float* __restrict__ o) {
  const int e = blockIdx.x;
  const int tid = threadIdx.x;
  const int lane = tid & 63, wave = tid >> 6;
  __shared__ float a_lds[CHUNK*IDIM];  // 24 KB
  __shared__ float o_lds[16*CHUNK];    // 0.5 KB
  __shared__ int list_s[S];
  __shared__ int n_s;

  BUILD_LIST(e)
  const int n = n_s;
  if (n == 0) return;
  const int row0 = blockIdx.y * 16;

  for (int c0 = 0; c0 < n; c0 += CHUNK) {
    const int cn = min(CHUNK, n - c0);
    for (int q = tid; q < cn*(IDIM/4); q += 256) {
      int j = q / (IDIM/4), p = q - j*(IDIM/4);
      int aid = list_s[c0+j];
      ((float4*)(a_lds + j*IDIM))[p] = ((const float4*)(act + (size_t)aid*IDIM))[p];
    }
    __syncthreads();

    {
      const int lrow = wave*4;
      const int r = row0 + lrow;
      float4 wv[4][3]; float bias[4];
#pragma unroll
      for (int rr = 0; rr < 4; ++rr) {
        const float4* row = (const float4*)(w2 + ((size_t)e*H + r + rr)*IDIM);
        wv[rr][0] = row[lane]; wv[rr][1] = row[lane+64]; wv[rr][2] = row[lane+128];
        bias[rr] = b2[(size_t)e*H + r + rr];
      }
      for (int j = 0; j < cn; ++j) {
        const float4* tv = (const float4*)(a_lds + j*IDIM);
        float4 x0 = tv[lane], x1 = tv[lane+64], x2 = tv[lane+128];
        float a0 = dot4(wv[0][0],x0) + dot4(wv[0][1],x1) + dot4(wv[0][2],x2);
        float a1 = dot4(wv[1][0],x0) + dot4(wv[1][1],x1) + dot4(wv[1][2],x2);
        float a2 = dot4(wv[2][0],x0) + dot4(wv[2][1],x1) + dot4(wv[2][2],x2);
        float a3 = dot4(wv[3][0],x0) + dot4(wv[3][1],x1) + dot4(wv[3][2],x2);
        float u = coreduce4(a0, a1, a2, a3, lane);
        const bool hi32 = (lane & 32) != 0, hi16 = (lane & 16) != 0;
        float bsel = hi32 ? (hi16 ? bias[3] : bias[2]) : (hi16 ? bias[1] : bias[0]);
        if ((lane & 15) == 0)
          o_lds[(lrow + (lane >> 4))*CHUNK + j] = u + bsel;
      }
    }
    __syncthreads();

    for (int q = tid; q < 16*cn; q += 256) {
      int rl = q & 15, j = q >> 4;
      int aid = list_s[c0 + j];
      o[(size_t)aid*H + row0 + rl] = o_lds[rl*CHUNK + j];
    }
    __syncthreads();
  }
}

// ---------------- kernel 4: weighted sum + residual ----------------
// deterministic: fixed k-order accumulation
__global__ void k_finalize(const float* __restrict__ x,
                           const float* __restrict__ o,
                           const float* __restrict__ wt,
                           float* __restrict__ out) {
  int g = blockIdx.x*256 + threadIdx.x;   // 0 .. S*H-1
  int b = g / H;
  int c = g - b*H;
  float acc = x[g];
#pragma unroll
  for (int k = 0; k < K; ++k)
    acc += wt[b*K + k] * o[(size_t)(b*K + k)*H + c];
  out[g] = acc;
}

extern "C" void kernel_launch(void* const* d_in, const int* in_sizes, int n_in,
                              void* d_out, int out_size, void* d_ws, size_t ws_size,
                              hipStream_t stream) {
  const float* x          = (const float*)d_in[0];
  const float* norm_scale = (const float*)d_in[1];
  const float* gate_w     = (const float*)d_in[2];
  const float* gate_b     = (const float*)d_in[3];
  const float* w1         = (const float*)d_in[4];
  const float* b1         = (const float*)d_in[5];
  const float* w2         = (const float*)d_in[6];
  const float* b2         = (const float*)d_in[7];
  float* out = (float*)d_out;

  // ws layout: t | wt | idx_all | act | o   (~885 KB)
  float* t       = (float*)d_ws;              // S*H      = 24576 f
  float* wt      = t + S*H;                   // S*K      = 128 f
  int*   idx_all = (int*)(wt + S*K);          // S*K      = 128 i
  float* act     = (float*)(idx_all + S*K);   // S*K*IDIM = 98304 f
  float* o       = act + S*K*IDIM;            // S*K*H    = 98304 f

  k_norm_router<<<S, 256, 0, stream>>>(x, norm_scale, gate_w, gate_b,
                                       t, wt, idx_all);
  dim3 g1(E, TWO_I/32);
  k_gemv1<<<g1, 256, 0, stream>>>(w1, b1, t, idx_all, act);
  dim3 g2(E, H/16);
  k_gemv2<<<g2, 256, 0, stream>>>(w2, b2, act, idx_all, o);
  k_finalize<<<(S*H)/256, 256, 0, stream>>>(x, o, wt, out);
}

// Round 5
// 303.532 us; speedup vs baseline: 1.0282x; 1.0282x over previous
//
#include <hip/hip_runtime.h>

#define S 32
#define H 768
#define IDIM 768
#define E 32
#define K 4
#define TWO_I 1536
#define LIMIT 7.0f
#define ALPHA 1.702f
#define EPS 1e-5f
#define CHUNK 8

__device__ inline float dot4(float4 a, float4 b) {
  return a.x*b.x + a.y*b.y + a.z*b.z + a.w*b.w;
}

// Co-reduce 4 per-lane accumulators across the 64-lane wave.
// Result: sum of acc g lives in all lanes of group [g*16, g*16+16).
__device__ inline float coreduce4(float a0, float a1, float a2, float a3, int lane) {
  const bool hi32 = (lane & 32) != 0;
  float s0 = hi32 ? a2 : a0;
  float o0 = hi32 ? a0 : a2;
  float s1 = hi32 ? a3 : a1;
  float o1 = hi32 ? a1 : a3;
  s0 += __shfl_xor(o0, 32);
  s1 += __shfl_xor(o1, 32);
  const bool hi16 = (lane & 16) != 0;
  float u  = hi16 ? s1 : s0;
  float ov = hi16 ? s0 : s1;
  u += __shfl_xor(ov, 16);
  u += __shfl_xor(u, 8);
  u += __shfl_xor(u, 4);
  u += __shfl_xor(u, 2);
  u += __shfl_xor(u, 1);
  return u;
}

// ---------------- kernel 1: RMSNorm + router + residual-init -------
// grid = S blocks, 256 threads
__global__ __launch_bounds__(256)
void k_norm_router(const float* __restrict__ x,
                   const float* __restrict__ norm_scale,
                   const float* __restrict__ gate_w,
                   const float* __restrict__ gate_b,
                   float* __restrict__ t_out,
                   float* __restrict__ wt_out,
                   int* __restrict__ idx_out,
                   float* __restrict__ out) {
  __shared__ float t_s[H];
  __shared__ float red_s[4];
  __shared__ float logit_s[E];
  const int b = blockIdx.x;
  const int tid = threadIdx.x;
  const int lane = tid & 63, wave = tid >> 6;

  float v0 = x[b*H + tid];
  float v1 = x[b*H + tid + 256];
  float v2 = x[b*H + tid + 512];
  // residual init: out starts as x (gemv2 atomically accumulates into it)
  out[b*H + tid]       = v0;
  out[b*H + tid + 256] = v1;
  out[b*H + tid + 512] = v2;
  float ss = v0*v0 + v1*v1 + v2*v2;
#pragma unroll
  for (int o = 32; o; o >>= 1) ss += __shfl_xor(ss, o);
  if (lane == 0) red_s[wave] = ss;
  __syncthreads();
  float mean = (red_s[0] + red_s[1] + red_s[2] + red_s[3]) * (1.0f/(float)H) + EPS;
  float rs = rsqrtf(mean);
  rs = rs * (1.5f - 0.5f*mean*rs*rs);   // Newton refine for fp32-accurate rsqrt
  float t0 = v0*rs*norm_scale[tid];
  float t1 = v1*rs*norm_scale[tid+256];
  float t2 = v2*rs*norm_scale[tid+512];
  t_s[tid] = t0; t_s[tid+256] = t1; t_s[tid+512] = t2;
  t_out[b*H+tid] = t0; t_out[b*H+tid+256] = t1; t_out[b*H+tid+512] = t2;
  __syncthreads();

  for (int e = wave; e < E; e += 4) {
    const float* gw = gate_w + e*H;
    float s = 0.f;
#pragma unroll
    for (int j = 0; j < H/64; ++j) {
      int p = lane + j*64;
      s += gw[p] * t_s[p];
    }
#pragma unroll
    for (int o = 32; o; o >>= 1) s += __shfl_xor(s, o);
    if (lane == 0) logit_s[e] = s + gate_b[e];
  }
  __syncthreads();

  if (tid == 0) {
    float lg[E];
    for (int e = 0; e < E; ++e) lg[e] = logit_s[e];
    float vals[K]; int idxs[K];
    for (int k = 0; k < K; ++k) {
      float best = -3.4e38f; int bi = 0;
      for (int e = 0; e < E; ++e)
        if (lg[e] > best) { best = lg[e]; bi = e; }  // strict > == lax.top_k tie-break
      vals[k] = best; idxs[k] = bi; lg[bi] = -3.4e38f;
    }
    float m = vals[0], sum = 0.f, w[K];
    for (int k = 0; k < K; ++k) { w[k] = expf(vals[k]-m); sum += w[k]; }
    float inv = 1.f/sum;
    for (int k = 0; k < K; ++k) {
      wt_out[b*K+k] = w[k]*inv;
      idx_out[b*K+k] = idxs[k];
    }
  }
}

// Deterministic per-expert assignment list via ballot compaction.
#define BUILD_LIST(eexpr)                                                   \
  if (tid < 64) {                                                           \
    int a0 = idx_all[tid];                                                  \
    int a1 = idx_all[tid + 64];                                             \
    unsigned long long m0 = __ballot(a0 == (eexpr));                        \
    unsigned long long m1 = __ballot(a1 == (eexpr));                        \
    unsigned long long below = (1ULL << tid) - 1ULL;                        \
    if (a0 == (eexpr)) list_s[__popcll(m0 & below)] = tid;                  \
    if (a1 == (eexpr)) list_s[__popcll(m0) + __popcll(m1 & below)] = tid + 64; \
    if (tid == 0) n_s = (int)(__popcll(m0) + __popcll(m1));                 \
  }                                                                         \
  __syncthreads();

// ---------------- kernel 2: expert-grouped GEMV1 + SwiGLU ----------
// grid = (E, TWO_I/16 = 96), 256 threads. 16 rows/block, 4 rows/wave.
// Weight loads hoisted to the top: HBM latency overlaps list-build/staging.
__global__ __launch_bounds__(256)
void k_gemv1(const float* __restrict__ w1,
             const float* __restrict__ b1,
             const float* __restrict__ t,
             const int* __restrict__ idx_all,
             float* __restrict__ act) {
  const int e = blockIdx.x;
  const int tid = threadIdx.x;
  const int lane = tid & 63, wave = tid >> 6;
  const int row0 = blockIdx.y * 16;
  const int r = row0 + wave*4;

  float4 wv[4][3]; float bias[4];
#pragma unroll
  for (int rr = 0; rr < 4; ++rr) {
    const float4* row = (const float4*)(w1 + ((size_t)e*TWO_I + r + rr)*H);
    wv[rr][0] = row[lane]; wv[rr][1] = row[lane+64]; wv[rr][2] = row[lane+128];
    bias[rr] = b1[(size_t)e*TWO_I + r + rr];
  }

  __shared__ float t_lds[CHUNK*H];   // 24 KB
  __shared__ float h_lds[16*CHUNK];  // 0.5 KB
  __shared__ int list_s[S];
  __shared__ int n_s;

  BUILD_LIST(e)
  const int n = n_s;
  if (n == 0) return;

  for (int c0 = 0; c0 < n; c0 += CHUNK) {
    const int cn = min(CHUNK, n - c0);
    for (int q = tid; q < cn*(H/4); q += 256) {
      int j = q / (H/4), p = q - j*(H/4);
      int bt = list_s[c0+j] >> 2;
      ((float4*)(t_lds + j*H))[p] = ((const float4*)(t + (size_t)bt*H))[p];
    }
    __syncthreads();

    for (int j = 0; j < cn; ++j) {
      const float4* tv = (const float4*)(t_lds + j*H);
      float4 x0 = tv[lane], x1 = tv[lane+64], x2 = tv[lane+128];
      float a0 = dot4(wv[0][0],x0) + dot4(wv[0][1],x1) + dot4(wv[0][2],x2);
      float a1 = dot4(wv[1][0],x0) + dot4(wv[1][1],x1) + dot4(wv[1][2],x2);
      float a2 = dot4(wv[2][0],x0) + dot4(wv[2][1],x1) + dot4(wv[2][2],x2);
      float a3 = dot4(wv[3][0],x0) + dot4(wv[3][1],x1) + dot4(wv[3][2],x2);
      float u = coreduce4(a0, a1, a2, a3, lane);
      const bool hi32 = (lane & 32) != 0, hi16 = (lane & 16) != 0;
      float bsel = hi32 ? (hi16 ? bias[3] : bias[2]) : (hi16 ? bias[1] : bias[0]);
      if ((lane & 15) == 0)
        h_lds[(wave*4 + (lane >> 4))*CHUNK + j] = u + bsel;
    }
    __syncthreads();

    // interleaved SwiGLU: local rows (2c, 2c+1) -> output col (row0>>1)+c
    for (int q = tid; q < 8*cn; q += 256) {
      int c = q & 7, j = q >> 3;
      float he = h_lds[(2*c)*CHUNK + j];
      float ho = h_lds[(2*c+1)*CHUNK + j];
      float xg = fminf(he, LIMIT);
      float xl = fminf(fmaxf(ho, -LIMIT), LIMIT);
      float sig = 1.f/(1.f + expf(-ALPHA*xg));
      int aid = list_s[c0 + j];
      act[(size_t)aid*IDIM + (row0 >> 1) + c] = xg*sig*(xl + 1.f);
    }
    __syncthreads();
  }
}

// ---------------- kernel 3: expert-grouped GEMV2 + weighted scatter -
// grid = (E, H/16 = 48), 256 threads. 16 rows/block, 4 rows/wave.
// Accumulates wt*o directly into out (pre-initialized to x).
__global__ __launch_bounds__(256)
void k_gemv2(const float* __restrict__ w2,
             const float* __restrict__ b2,
             const float* __restrict__ act,
             const int* __restrict__ idx_all,
             const float* __restrict__ wt,
             float* __restrict__ out) {
  const int e = blockIdx.x;
  const int tid = threadIdx.x;
  const int lane = tid & 63, wave = tid >> 6;
  const int row0 = blockIdx.y * 16;
  const int r = row0 + wave*4;

  float4 wv[4][3]; float bias[4];
#pragma unroll
  for (int rr = 0; rr < 4; ++rr) {
    const float4* row = (const float4*)(w2 + ((size_t)e*H + r + rr)*IDIM);
    wv[rr][0] = row[lane]; wv[rr][1] = row[lane+64]; wv[rr][2] = row[lane+128];
    bias[rr] = b2[(size_t)e*H + r + rr];
  }

  __shared__ float a_lds[CHUNK*IDIM];  // 24 KB
  __shared__ int list_s[S];
  __shared__ int n_s;

  BUILD_LIST(e)
  const int n = n_s;
  if (n == 0) return;

  for (int c0 = 0; c0 < n; c0 += CHUNK) {
    const int cn = min(CHUNK, n - c0);
    for (int q = tid; q < cn*(IDIM/4); q += 256) {
      int j = q / (IDIM/4), p = q - j*(IDIM/4);
      int aid = list_s[c0+j];
      ((float4*)(a_lds + j*IDIM))[p] = ((const float4*)(act + (size_t)aid*IDIM))[p];
    }
    __syncthreads();

    for (int j = 0; j < cn; ++j) {
      const float4* tv = (const float4*)(a_lds + j*IDIM);
      float4 x0 = tv[lane], x1 = tv[lane+64], x2 = tv[lane+128];
      float a0 = dot4(wv[0][0],x0) + dot4(wv[0][1],x1) + dot4(wv[0][2],x2);
      float a1 = dot4(wv[1][0],x0) + dot4(wv[1][1],x1) + dot4(wv[1][2],x2);
      float a2 = dot4(wv[2][0],x0) + dot4(wv[2][1],x1) + dot4(wv[2][2],x2);
      float a3 = dot4(wv[3][0],x0) + dot4(wv[3][1],x1) + dot4(wv[3][2],x2);
      float u = coreduce4(a0, a1, a2, a3, lane);
      const bool hi32 = (lane & 32) != 0, hi16 = (lane & 16) != 0;
      float bsel = hi32 ? (hi16 ? bias[3] : bias[2]) : (hi16 ? bias[1] : bias[0]);
      if ((lane & 15) == 0) {
        int aid = list_s[c0 + j];
        int bt = aid >> 2;
        atomicAdd(&out[bt*H + r + (lane >> 4)], wt[aid] * (u + bsel));
      }
    }
    __syncthreads();
  }
}

extern "C" void kernel_launch(void* const* d_in, const int* in_sizes, int n_in,
                              void* d_out, int out_size, void* d_ws, size_t ws_size,
                              hipStream_t stream) {
  const float* x          = (const float*)d_in[0];
  const float* norm_scale = (const float*)d_in[1];
  const float* gate_w     = (const float*)d_in[2];
  const float* gate_b     = (const float*)d_in[3];
  const float* w1         = (const float*)d_in[4];
  const float* b1         = (const float*)d_in[5];
  const float* w2         = (const float*)d_in[6];
  const float* b2         = (const float*)d_in[7];
  float* out = (float*)d_out;

  // ws layout: t | wt | idx_all | act   (~0.5 MB)
  float* t       = (float*)d_ws;              // S*H      = 24576 f
  float* wt      = t + S*H;                   // S*K      = 128 f
  int*   idx_all = (int*)(wt + S*K);          // S*K      = 128 i
  float* act     = (float*)(idx_all + S*K);   // S*K*IDIM = 98304 f

  k_norm_router<<<S, 256, 0, stream>>>(x, norm_scale, gate_w, gate_b,
                                       t, wt, idx_all, out);
  dim3 g1(E, TWO_I/16);
  k_gemv1<<<g1, 256, 0, stream>>>(w1, b1, t, idx_all, act);
  dim3 g2(E, H/16);
  k_gemv2<<<g2, 256, 0, stream>>>(w2, b2, act, idx_all, wt, out);
}